// Round 7
// baseline (565.612 us; speedup 1.0000x reference)
//
#include <hip/hip_runtime.h>
#include <math.h>

#define SB 1024   // seq len
#define DM 1024   // d_model
#define BB 4      // batch
#define NH 16     // heads
#define DH 64     // head dim
#define ML 1024   // MAX_LEN

typedef __attribute__((ext_vector_type(8))) short short8;
typedef __attribute__((ext_vector_type(8))) _Float16 half8;
typedef __attribute__((ext_vector_type(4))) float f32x4;
typedef unsigned short u16;

__device__ __forceinline__ u16 f2bf(float x) {
  unsigned u = __float_as_uint(x);
  u += 0x7fffu + ((u >> 16) & 1u);
  return (u16)(u >> 16);
}
__device__ __forceinline__ float bf2f(u16 h) { return __uint_as_float((unsigned)h << 16); }

// async global->LDS, 16B per lane; lds base must be wave-uniform (HW adds lane*16)
__device__ __forceinline__ void async16(void* lds, const void* g) {
  __builtin_amdgcn_global_load_lds(
      (const __attribute__((address_space(1))) unsigned*)g,
      (__attribute__((address_space(3))) unsigned*)lds, 16, 0, 0);
}

// ---------------- sinusoidal positional encoding ----------------
__global__ void pe_kernel(float* __restrict__ pe) {
  int p = blockIdx.x;
  for (int i = threadIdx.x; i < DM / 2; i += 256) {
    float div = expf((float)(2 * i) * (-9.210340371976184f / (float)DM));
    float ang = (float)p * div;
    pe[(size_t)p * DM + 2 * i]     = sinf(ang);
    pe[(size_t)p * DM + 2 * i + 1] = cosf(ang);
  }
}

// ---------------- layernorm (fp32 out) ----------------
__device__ __forceinline__ float block_sum256(float s, float* red) {
  #pragma unroll
  for (int o = 32; o > 0; o >>= 1) s += __shfl_down(s, o, 64);
  int t = threadIdx.x;
  if ((t & 63) == 0) red[t >> 6] = s;
  __syncthreads();
  float tot = red[0] + red[1] + red[2] + red[3];
  __syncthreads();
  return tot;
}

__global__ __launch_bounds__(256) void ln_kernel(const float* __restrict__ x,
    const float* __restrict__ gamma, const float* __restrict__ beta,
    float* __restrict__ xn) {
  __shared__ float red[4];
  int row = blockIdx.x;
  const float4* xr = (const float4*)(x + (size_t)row * DM);
  int t = threadIdx.x;
  float4 v = xr[t];
  float mu = block_sum256(v.x + v.y + v.z + v.w, red) * (1.0f / DM);
  float4 d = {v.x - mu, v.y - mu, v.z - mu, v.w - mu};
  float var = block_sum256(d.x*d.x + d.y*d.y + d.z*d.z + d.w*d.w, red) * (1.0f / DM);
  float rstd = rsqrtf(var + 1e-5f);
  float4 g  = ((const float4*)gamma)[t];
  float4 bb = ((const float4*)beta)[t];
  float4 o = {d.x * rstd * g.x + bb.x, d.y * rstd * g.y + bb.y,
              d.z * rstd * g.z + bb.z, d.w * rstd * g.w + bb.w};
  ((float4*)(xn + (size_t)row * DM))[t] = o;
}

// ---------------- pack fp32 [R][1024] -> split-fp16 frag-chunk planes ----------------
__global__ __launch_bounds__(256) void pack16(const float* __restrict__ src,
    _Float16* __restrict__ dH, _Float16* __restrict__ dL, float scale) {
  int rt = blockIdx.x;
  int t = threadIdx.x;
  int r16 = t >> 4, ks = t & 15;
  const float* sp = src + (size_t)(rt * 16 + r16) * 1024 + ks * 64;
  float v[64];
  #pragma unroll
  for (int i = 0; i < 16; ++i) {
    float4 f = *(const float4*)(sp + i * 4);
    v[i*4+0] = f.x; v[i*4+1] = f.y; v[i*4+2] = f.z; v[i*4+3] = f.w;
  }
  #pragma unroll
  for (int hf = 0; hf < 2; ++hf) {
    int kt = ks * 2 + hf;
    #pragma unroll
    for (int gg = 0; gg < 4; ++gg) {
      half8 hv, lv;
      #pragma unroll
      for (int j = 0; j < 8; ++j) {
        float x = v[hf * 32 + gg * 8 + j] * scale;
        _Float16 h = (_Float16)x;
        hv[j] = h;
        lv[j] = (_Float16)(x - (float)h);
      }
      size_t off = ((size_t)(rt * 32 + kt) * 64 + r16 + gg * 16) * 8;
      *(half8*)(dH + off) = hv;
      *(half8*)(dL + off) = lv;
    }
  }
}

// ---------------- split-fp16 MFMA GEMM ----------------
#define GBM 128
#define GBN 256

__global__ __launch_bounds__(256, 2) void gemm16(
    const _Float16* __restrict__ AH, const _Float16* __restrict__ AL,
    const _Float16* __restrict__ BH, const _Float16* __restrict__ BL,
    u16* __restrict__ o0H, u16* __restrict__ o0L, float s0,
    u16* __restrict__ o1H, u16* __restrict__ o1L, float s1,
    u16* __restrict__ o2H, u16* __restrict__ o2L, float s2) {
  __shared__ _Float16 L[32 * 512];
  int t = threadIdx.x;
  int wv = t >> 6, lane = t & 63;
  int wm = wv >> 1, wn = wv & 1;
  int r16 = lane & 15, g = lane >> 4;
  int m0 = blockIdx.y * GBM;
  int n0 = blockIdx.x * GBN;
  int mt0 = m0 >> 4, nt0 = n0 >> 4;

  f32x4 acc[4][8];
  #pragma unroll
  for (int i = 0; i < 4; ++i)
    #pragma unroll
    for (int j = 0; j < 8; ++j) acc[i][j] = (f32x4){0.f, 0.f, 0.f, 0.f};

  for (int kt = 0; kt < 32; ++kt) {
    __syncthreads();
    #pragma unroll
    for (int rd = 0; rd < 8; ++rd) {
      int ci = rd * 4 + wv;
      const _Float16* src;
      if (ci < 16) {
        int mt = ci >> 1, pl = ci & 1;
        const _Float16* P = pl ? AL : AH;
        src = P + ((size_t)((mt0 + mt) * 32 + kt) * 64 + lane) * 8;
      } else {
        int nt = ci - 16;
        src = BH + ((size_t)((nt0 + nt) * 32 + kt) * 64 + lane) * 8;
      }
      async16(&L[ci * 512], src);
    }
    half8 blo[8];
    #pragma unroll
    for (int j = 0; j < 8; ++j) {
      int ntg = nt0 + wn * 8 + j;
      blo[j] = *(const half8*)(BL + ((size_t)(ntg * 32 + kt) * 64 + lane) * 8);
    }
    __syncthreads();

    half8 ah[4], al[4];
    #pragma unroll
    for (int i = 0; i < 4; ++i) {
      ah[i] = *(const half8*)&L[(((wm * 4 + i) * 2 + 0) * 512) + lane * 8];
      al[i] = *(const half8*)&L[(((wm * 4 + i) * 2 + 1) * 512) + lane * 8];
    }
    #pragma unroll
    for (int j = 0; j < 8; ++j) {
      half8 bh = *(const half8*)&L[((16 + wn * 8 + j) * 512) + lane * 8];
      #pragma unroll
      for (int i = 0; i < 4; ++i) {
        acc[i][j] = __builtin_amdgcn_mfma_f32_16x16x32_f16(ah[i], bh, acc[i][j], 0, 0, 0);
        acc[i][j] = __builtin_amdgcn_mfma_f32_16x16x32_f16(al[i], bh, acc[i][j], 0, 0, 0);
        acc[i][j] = __builtin_amdgcn_mfma_f32_16x16x32_f16(ah[i], blo[j], acc[i][j], 0, 0, 0);
      }
    }
  }

  #pragma unroll
  for (int i = 0; i < 4; ++i)
    #pragma unroll
    for (int j = 0; j < 8; ++j) {
      int col = n0 + wn * 128 + j * 16 + r16;
      int band = col >> 10, lc = col & 1023;
      float sc = band == 0 ? s0 : band == 1 ? s1 : s2;
      u16* oh = band == 0 ? o0H : band == 1 ? o1H : o2H;
      u16* ol = band == 0 ? o0L : band == 1 ? o1L : o2L;
      #pragma unroll
      for (int reg = 0; reg < 4; ++reg) {
        int row = m0 + wm * 64 + i * 16 + g * 4 + reg;
        float c = acc[i][j][reg] * sc;
        u16 hi = f2bf(c);
        oh[(size_t)row * 1024 + lc] = hi;
        if (ol) ol[(size_t)row * 1024 + lc] = f2bf(c - bf2f(hi));
      }
    }
}

// ---------------- pack V (bf16 [B*S][1024] cols h*64+d) -> frag chunks ----------------
__global__ __launch_bounds__(256) void pack_v(const u16* __restrict__ VHg,
    u16* __restrict__ Vf) {
  int sg = blockIdx.x;
  int h = blockIdx.y, b = blockIdx.z;
  int bh = b * NH + h;
  int t = threadIdx.x;
  int r = t >> 2, q = t & 3;
  int s = sg * 64 + r;
  int kc = s >> 5, g = (s >> 3) & 3, j = s & 7;
  const u16* sp = VHg + (size_t)(b * SB + s) * 1024 + h * 64 + q * 16;
  u16 vv[16];
  *(short8*)&vv[0] = *(const short8*)sp;
  *(short8*)&vv[8] = *(const short8*)(sp + 8);
  u16* dp = Vf + ((size_t)(bh * 32 + kc) * 4 + q) * 512 + g * 128 + j;
  #pragma unroll
  for (int e = 0; e < 16; ++e) dp[e * 8] = vv[e];
}

// ---------------- pack K split-bf16 planes -> MFMA B-frag chunks ----------------
__global__ __launch_bounds__(256) void pack_kf(
    const u16* __restrict__ KH, const u16* __restrict__ KL,
    const u16* __restrict__ pKH, const u16* __restrict__ pKL,
    u16* __restrict__ KtfH, u16* __restrict__ KtfL,
    u16* __restrict__ KpfH, u16* __restrict__ KpfL) {
  int sq = blockIdx.x;
  int h = blockIdx.y, z = blockIdx.z;
  int t = threadIdx.x;
  int u = t >> 6, lane = t & 63;
  #pragma unroll
  for (int it = 0; it < 16; ++it) {
    int uu = it * 4 + u;
    int stl = uu >> 2, c = (uu >> 1) & 1, pl = uu & 1;
    int st = sq * 16 + stl;
    size_t roff = (size_t)(st * 16 + (lane & 15)) * 1024 + h * 64 + c * 32 + (lane >> 4) * 8;
    const u16* src;
    u16* dst;
    if (z < BB) {
      src = (pl ? KL : KH) + (size_t)z * SB * 1024 + roff;
      dst = (pl ? KtfL : KtfH) + ((size_t)((z * NH + h) * 64 + st) * 2 + c) * 512 + lane * 8;
    } else {
      src = (pl ? pKL : pKH) + roff;
      dst = (pl ? KpfL : KpfH) + ((size_t)(h * 64 + st) * 2 + c) * 512 + lane * 8;
    }
    *(short8*)dst = *(const short8*)src;
  }
}

// ---------------- bias table transpose: btT[h][rel] ----------------
__global__ __launch_bounds__(256) void btt_kernel(
    const float* __restrict__ bt, float* __restrict__ btT) {
  int h = blockIdx.x;
  for (int r = threadIdx.x; r < 2 * ML; r += 256)
    btT[(size_t)h * (2 * ML) + r] = bt[(size_t)r * NH + h];
}

// ---------------- MFMA flash attention v5: split-k=2, deferred l-reduce ----------------
// blockIdx.y = k-split (0: k<512 -> writes d_out; 1: k>=512 -> writes O1).
// Output is UNNORMALIZED O plus per-row (m, l); combine kernel merges.
// __launch_bounds__(256,8): VGPR<=64 so 8 blocks/CU (32 waves/CU) are resident.
__global__ __launch_bounds__(256, 8) void attn_mfma5(
    const u16* __restrict__ KtfH, const u16* __restrict__ KtfL,  // [BH][64][2][512]
    const u16* __restrict__ KpfH, const u16* __restrict__ KpfL,  // [H][64][2][512]
    const u16* __restrict__ QHg, const u16* __restrict__ QLg,    // [B*S][1024] (x IS)
    const u16* __restrict__ pQH, const u16* __restrict__ pQL,    // [S][1024] (x IS)
    const u16* __restrict__ Vf,                                   // [BH][32][4][512]
    const float* __restrict__ btT,
    float* __restrict__ O0, float* __restrict__ O1,              // unnormalized partials
    float2* __restrict__ ml) {                                    // [2][BH][S]
  __shared__ u16 Pb[4][16 * 72];
  int bid = blockIdx.x;
  int sp  = blockIdx.y;
  int qt = bid & 15;
  int h  = (bid >> 4) & 15;
  int b  = bid >> 8;
  int q0 = qt * 64;
  int t = threadIdx.x;
  int wv = t >> 6, lane = t & 63;
  int g = lane >> 4, r16 = lane & 15;
  int bh = b * NH + h;

  // ---- Q fragments (A-layout), hi/lo straight from split planes
  int qrow = q0 + wv * 16 + r16;
  short8 qhi[4], qlo[4];
  #pragma unroll
  for (int c = 0; c < 4; ++c) {
    if (c < 2) {
      size_t off = (size_t)(b * SB + qrow) * 1024 + h * DH + c * 32 + g * 8;
      qhi[c] = *(const short8*)(QHg + off);
      qlo[c] = *(const short8*)(QLg + off);
    } else {
      size_t off = (size_t)qrow * 1024 + h * DH + (c - 2) * 32 + g * 8;
      qhi[c] = *(const short8*)(pQH + off);
      qlo[c] = *(const short8*)(pQL + off);
    }
  }

  f32x4 O[4];
  #pragma unroll
  for (int dt = 0; dt < 4; ++dt) O[dt] = (f32x4){0.f, 0.f, 0.f, 0.f};
  float m_run[4] = {-3e38f, -3e38f, -3e38f, -3e38f};
  float l_run[4] = {0.f, 0.f, 0.f, 0.f};   // lane-local partial sums (deferred reduce)

  int qbase = q0 + wv * 16 + g * 4;
  // Incrementing pointers: per-kt strides are compile-time constants.
  const u16* ktH = KtfH + ((size_t)(bh * 64) + sp * 32) * 1024 + lane * 8;
  const u16* ktL = KtfL + ((size_t)(bh * 64) + sp * 32) * 1024 + lane * 8;
  const u16* kpH = KpfH + ((size_t)(h * 64) + sp * 32) * 1024 + lane * 8;
  const u16* kpL = KpfL + ((size_t)(h * 64) + sp * 32) * 1024 + lane * 8;
  const u16* vp  = Vf + ((size_t)(bh * 32) + sp * 16) * 2048 + lane * 8;
  const float* bp = btT + (size_t)h * (2 * ML) + ML + sp * 512 + r16 - qbase;

  for (int ktr = 0; ktr < 8; ++ktr) {
    // ---- bias gathers first (independent, prefetchable)
    float bias[4][4];
    #pragma unroll
    for (int nt = 0; nt < 4; ++nt)
      #pragma unroll
      for (int reg = 0; reg < 4; ++reg)
        bias[nt][reg] = bp[nt * 16 - reg];

    // ---- QK^T: S = (Qhi+Qlo).(Khi+Klo), 3-term, B-frags direct from global
    f32x4 S[4];
    #pragma unroll
    for (int nt = 0; nt < 4; ++nt) {
      f32x4 acc = (f32x4){0.f, 0.f, 0.f, 0.f};
      #pragma unroll
      for (int c = 0; c < 4; ++c) {
        const u16* ph = (c < 2) ? ktH : kpH;
        const u16* pl = (c < 2) ? ktL : kpL;
        int co = (c < 2) ? c : (c - 2);
        short8 bhi = *(const short8*)(ph + nt * 1024 + co * 512);
        short8 blo = *(const short8*)(pl + nt * 1024 + co * 512);
        acc = __builtin_amdgcn_mfma_f32_16x16x32_bf16(qhi[c], bhi, acc, 0, 0, 0);
        acc = __builtin_amdgcn_mfma_f32_16x16x32_bf16(qlo[c], bhi, acc, 0, 0, 0);
        acc = __builtin_amdgcn_mfma_f32_16x16x32_bf16(qhi[c], blo, acc, 0, 0, 0);
      }
      S[nt] = acc;
    }

    // ---- V prefetch: consumed after softmax
    short8 vfrag[2][4];
    #pragma unroll
    for (int kc = 0; kc < 2; ++kc)
      #pragma unroll
      for (int dt = 0; dt < 4; ++dt)
        vfrag[kc][dt] = *(const short8*)(vp + (kc * 4 + dt) * 512);

    // ---- bias add
    #pragma unroll
    for (int nt = 0; nt < 4; ++nt)
      #pragma unroll
      for (int reg = 0; reg < 4; ++reg)
        S[nt][reg] += bias[nt][reg];

    // ---- online softmax: only the MAX needs cross-lane reduce per kt
    float tm[4], al[4];
    #pragma unroll
    for (int reg = 0; reg < 4; ++reg)
      tm[reg] = fmaxf(fmaxf(S[0][reg], S[1][reg]), fmaxf(S[2][reg], S[3][reg]));
    #pragma unroll
    for (int off = 1; off < 16; off <<= 1)
      #pragma unroll
      for (int reg = 0; reg < 4; ++reg)
        tm[reg] = fmaxf(tm[reg], __shfl_xor(tm[reg], off, 64));
    #pragma unroll
    for (int reg = 0; reg < 4; ++reg) {
      float mn = fmaxf(m_run[reg], tm[reg]);
      al[reg] = __expf(m_run[reg] - mn);
      m_run[reg] = mn;
    }
    float ts[4] = {0.f, 0.f, 0.f, 0.f};
    #pragma unroll
    for (int nt = 0; nt < 4; ++nt)
      #pragma unroll
      for (int reg = 0; reg < 4; ++reg) {
        float p = __expf(S[nt][reg] - m_run[reg]);
        S[nt][reg] = p;
        ts[reg] += p;
      }
    #pragma unroll
    for (int reg = 0; reg < 4; ++reg)
      l_run[reg] = l_run[reg] * al[reg] + ts[reg];   // lane-local partial
    #pragma unroll
    for (int dt = 0; dt < 4; ++dt)
      #pragma unroll
      for (int reg = 0; reg < 4; ++reg)
        O[dt][reg] *= al[reg];

    // ---- P (C-layout) -> per-wave LDS -> A-layout frags (wave-local ordering)
    u16* pb = Pb[wv];
    #pragma unroll
    for (int nt = 0; nt < 4; ++nt)
      #pragma unroll
      for (int reg = 0; reg < 4; ++reg)
        pb[(g * 4 + reg) * 72 + nt * 16 + r16] = f2bf(S[nt][reg]);

    // ---- PV with prefetched V frags
    #pragma unroll
    for (int kc = 0; kc < 2; ++kc) {
      short8 pa = *(const short8*)&pb[r16 * 72 + kc * 32 + g * 8];
      #pragma unroll
      for (int dt = 0; dt < 4; ++dt)
        O[dt] = __builtin_amdgcn_mfma_f32_16x16x32_bf16(pa, vfrag[kc][dt], O[dt], 0, 0, 0);
    }

    ktH += 4096; ktL += 4096; kpH += 4096; kpL += 4096;
    vp += 4096; bp += 64;
  }

  // ---- final l reduction across the 16-lane column group
  #pragma unroll
  for (int off = 1; off < 16; off <<= 1)
    #pragma unroll
    for (int reg = 0; reg < 4; ++reg)
      l_run[reg] += __shfl_xor(l_run[reg], off, 64);

  // ---- write unnormalized partial O + (m, l)
  float* op = sp ? O1 : O0;
  #pragma unroll
  for (int dt = 0; dt < 4; ++dt)
    #pragma unroll
    for (int reg = 0; reg < 4; ++reg)
      op[(size_t)(b * SB + qbase + reg) * DM + h * DH + dt * 16 + r16] = O[dt][reg];
  if (r16 == 0) {
    #pragma unroll
    for (int reg = 0; reg < 4; ++reg)
      ml[(size_t)(sp * 64 + bh) * SB + qbase + reg] = make_float2(m_run[reg], l_run[reg]);
  }
}

// ---------------- combine the two k-splits ----------------
__global__ __launch_bounds__(256) void combine_kernel(
    float* __restrict__ out, const float* __restrict__ O1,
    const float2* __restrict__ ml) {
  int row = blockIdx.x;              // b*SB + q
  int b = row >> 10, q = row & 1023;
  int t = threadIdx.x;
  int h = t >> 4;                    // d = t*4 .. t*4+3 -> h = t>>4
  int bh = b * NH + h;
  float2 a0 = ml[(size_t)bh * SB + q];
  float2 a1 = ml[(size_t)(64 + bh) * SB + q];
  float M = fmaxf(a0.x, a1.x);
  float w0 = __expf(a0.x - M), w1 = __expf(a1.x - M);
  float inv = 1.0f / (a0.y * w0 + a1.y * w1);
  float4 c0 = *(const float4*)(out + (size_t)row * DM + t * 4);
  float4 c1 = *(const float4*)(O1 + (size_t)row * DM + t * 4);
  float4 r = {(c0.x * w0 + c1.x * w1) * inv, (c0.y * w0 + c1.y * w1) * inv,
              (c0.z * w0 + c1.z * w1) * inv, (c0.w * w0 + c1.w * w1) * inv};
  *(float4*)(out + (size_t)row * DM + t * 4) = r;
}

extern "C" void kernel_launch(void* const* d_in, const int* in_sizes, int n_in,
                              void* d_out, int out_size, void* d_ws, size_t ws_size,
                              hipStream_t stream) {
  const float* x     = (const float*)d_in[0];
  const float* gamma = (const float*)d_in[1];
  const float* beta  = (const float*)d_in[2];
  const float* w_pos = (const float*)d_in[3];
  const float* w_tok = (const float*)d_in[4];
  const float* bt    = (const float*)d_in[5];
  float* out = (float*)d_out;
  float* ws  = (float*)d_ws;
  const unsigned M1 = 1u << 20;
  const float IS = 11.313708498984761f;  // sqrt(2*dh)

  // Workspace (f32 units, 19M = 76 MB; overlays only on dead regions):
  float*    PE    = ws;                               // [0,1M)    dead after pack16
  _Float16* peH   = (_Float16*)(ws + 1 * M1);         // [1,1.5M)  dead after pos gemm
  _Float16* peL   = (_Float16*)(ws + 1 * M1 + M1/2);  // [1.5,2M)
  _Float16* wpH   = (_Float16*)(ws + 2 * M1);         // [2,3M)    dead after pos gemm
  _Float16* wpL   = (_Float16*)(ws + 3 * M1);         // [3,4M)
  u16*      posKH = (u16*)(ws + 4 * M1);              // [4,4.5M)  dead after pack_kf
  u16*      posKL = (u16*)(ws + 4 * M1 + M1/2);       // [4.5,5M)
  u16*      posQH = (u16*)(ws + 5 * M1);              // [5,5.5M)  live -> attn
  u16*      posQL = (u16*)(ws + 5 * M1 + M1/2);       // [5.5,6M)
  float*    XN    = ws + 6 * M1;                      // [6,10M)   dead after pack16
  _Float16* xnH   = (_Float16*)(ws + 10 * M1);        // [10,12M)  dead after tok gemm
  _Float16* xnL   = (_Float16*)(ws + 12 * M1);        // [12,14M)  dead after tok gemm
  _Float16* wtH   = (_Float16*)(ws + 14 * M1);        // [14,15.5M) dead after tok gemm
  _Float16* wtL   = (_Float16*)(ws + 15 * M1 + M1/2); // [15.5,17M)
  u16*      KH    = (u16*)(ws);                       // [0,2M)    over PE/peHL; dead after pack_kf
  u16*      KL    = (u16*)(ws + 2 * M1);              // [2,4M)    over wpHL; dead after pack_kf
  u16*      QH    = (u16*)(ws + 6 * M1);              // [6,8M)    over XN; live -> attn
  u16*      QL    = (u16*)(ws + 8 * M1);              // [8,10M)
  u16*      VH    = (u16*)(ws + 17 * M1);             // [17,19M)  dead after pack_v
  u16*      Vf    = (u16*)(ws + 10 * M1);             // [10,12M)  over xnH; live -> attn
  float*    btT   = ws + 12 * M1;                     // [12,12.25M) over xnL
  u16*      KpfH  = (u16*)(ws + 12 * M1 + M1/4);      // [12.25,12.75M) 2 MB
  u16*      KpfL  = (u16*)(ws + 12 * M1 + 3*M1/4);    // [12.75,13.25M)
  u16*      KtfH  = (u16*)(ws + 13 * M1 + M1/4);      // [13.25,15.25M) 8 MB
  u16*      KtfL  = (u16*)(ws + 15 * M1 + M1/4);      // [15.25,17.25M)
  float*    O1p   = ws;                               // [0,4M) 16 MB, over KH/KL (dead at attn)
  float2*   mlp   = (float2*)(ws + 4 * M1);           // [4,4.25M) 1 MB, over posK (dead at attn)

  pe_kernel<<<SB, 256, 0, stream>>>(PE);
  pack16<<<SB / 16, 256, 0, stream>>>(PE, peH, peL, 1.0f);
  pack16<<<(2 * DM) / 16, 256, 0, stream>>>(w_pos, wpH, wpL, 32.0f);
  gemm16<<<dim3((2 * DM) / GBN, SB / GBM), 256, 0, stream>>>(
      peH, peL, wpH, wpL,
      posKH, posKL, 1.0f / 32.0f,
      posQH, posQL, IS / 32.0f,
      posKH, posKL, 1.0f / 32.0f);
  ln_kernel<<<BB * SB, 256, 0, stream>>>(x, gamma, beta, XN);
  pack16<<<(BB * SB) / 16, 256, 0, stream>>>(XN, xnH, xnL, 1.0f);
  pack16<<<(3 * DM) / 16, 256, 0, stream>>>(w_tok, wtH, wtL, 32.0f);
  gemm16<<<dim3((3 * DM) / GBN, (BB * SB) / GBM), 256, 0, stream>>>(
      xnH, xnL, wtH, wtL,
      KH, KL, 1.0f / 32.0f,
      QH, QL, IS / 32.0f,
      VH, (u16*)nullptr, 1.0f / 32.0f);
  pack_v<<<dim3(SB / 64, NH, BB), 256, 0, stream>>>(VH, Vf);   // must precede pack_kf (KtfL overlays VH head)
  pack_kf<<<dim3(4, NH, BB + 1), 256, 0, stream>>>(KH, KL, posKH, posKL,
                                                   KtfH, KtfL, KpfH, KpfL);
  btt_kernel<<<NH, 256, 0, stream>>>(bt, btT);
  attn_mfma5<<<dim3(BB * NH * (SB / 64), 2), 256, 0, stream>>>(
      KtfH, KtfL, KpfH, KpfL, QH, QL, posQH, posQL, Vf, btT, out, O1p, mlp);
  combine_kernel<<<BB * SB, 256, 0, stream>>>(out, O1p, mlp);
}

// Round 8
// 464.256 us; speedup vs baseline: 1.2183x; 1.2183x over previous
//
#include <hip/hip_runtime.h>
#include <math.h>

#define SB 1024   // seq len
#define DM 1024   // d_model
#define BB 4      // batch
#define NH 16     // heads
#define DH 64     // head dim
#define ML 1024   // MAX_LEN

typedef __attribute__((ext_vector_type(8))) short short8;
typedef __attribute__((ext_vector_type(8))) _Float16 half8;
typedef __attribute__((ext_vector_type(4))) float f32x4;
typedef unsigned short u16;

__device__ __forceinline__ u16 f2bf(float x) {
  unsigned u = __float_as_uint(x);
  u += 0x7fffu + ((u >> 16) & 1u);
  return (u16)(u >> 16);
}
__device__ __forceinline__ float bf2f(u16 h) { return __uint_as_float((unsigned)h << 16); }

// async global->LDS, 16B per lane; lds base must be wave-uniform (HW adds lane*16)
__device__ __forceinline__ void async16(void* lds, const void* g) {
  __builtin_amdgcn_global_load_lds(
      (const __attribute__((address_space(1))) unsigned*)g,
      (__attribute__((address_space(3))) unsigned*)lds, 16, 0, 0);
}

// ---------------- layernorm (fp32 out) ----------------
__device__ __forceinline__ float block_sum256(float s, float* red) {
  #pragma unroll
  for (int o = 32; o > 0; o >>= 1) s += __shfl_down(s, o, 64);
  int t = threadIdx.x;
  if ((t & 63) == 0) red[t >> 6] = s;
  __syncthreads();
  float tot = red[0] + red[1] + red[2] + red[3];
  __syncthreads();
  return tot;
}

__global__ __launch_bounds__(256) void ln_kernel(const float* __restrict__ x,
    const float* __restrict__ gamma, const float* __restrict__ beta,
    float* __restrict__ xn) {
  __shared__ float red[4];
  int row = blockIdx.x;
  const float4* xr = (const float4*)(x + (size_t)row * DM);
  int t = threadIdx.x;
  float4 v = xr[t];
  float mu = block_sum256(v.x + v.y + v.z + v.w, red) * (1.0f / DM);
  float4 d = {v.x - mu, v.y - mu, v.z - mu, v.w - mu};
  float var = block_sum256(d.x*d.x + d.y*d.y + d.z*d.z + d.w*d.w, red) * (1.0f / DM);
  float rstd = rsqrtf(var + 1e-5f);
  float4 g  = ((const float4*)gamma)[t];
  float4 bb = ((const float4*)beta)[t];
  float4 o = {d.x * rstd * g.x + bb.x, d.y * rstd * g.y + bb.y,
              d.z * rstd * g.z + bb.z, d.w * rstd * g.w + bb.w};
  ((float4*)(xn + (size_t)row * DM))[t] = o;
}

// ---------------- pack fp32 [R][1024] -> split-fp16 frag-chunk planes ----------------
__global__ __launch_bounds__(256) void pack16(const float* __restrict__ src,
    _Float16* __restrict__ dH, _Float16* __restrict__ dL, float scale) {
  int rt = blockIdx.x;
  int t = threadIdx.x;
  int r16 = t >> 4, ks = t & 15;
  const float* sp = src + (size_t)(rt * 16 + r16) * 1024 + ks * 64;
  float v[64];
  #pragma unroll
  for (int i = 0; i < 16; ++i) {
    float4 f = *(const float4*)(sp + i * 4);
    v[i*4+0] = f.x; v[i*4+1] = f.y; v[i*4+2] = f.z; v[i*4+3] = f.w;
  }
  #pragma unroll
  for (int hf = 0; hf < 2; ++hf) {
    int kt = ks * 2 + hf;
    #pragma unroll
    for (int gg = 0; gg < 4; ++gg) {
      half8 hv, lv;
      #pragma unroll
      for (int j = 0; j < 8; ++j) {
        float x = v[hf * 32 + gg * 8 + j] * scale;
        _Float16 h = (_Float16)x;
        hv[j] = h;
        lv[j] = (_Float16)(x - (float)h);
      }
      size_t off = ((size_t)(rt * 32 + kt) * 64 + r16 + gg * 16) * 8;
      *(half8*)(dH + off) = hv;
      *(half8*)(dL + off) = lv;
    }
  }
}

// ---------------- fused: sinusoidal PE -> split-fp16 frag planes ----------------
__global__ __launch_bounds__(256) void pe_pack16(_Float16* __restrict__ dH,
    _Float16* __restrict__ dL) {
  int rt = blockIdx.x;
  int t = threadIdx.x;
  int r16 = t >> 4, ks = t & 15;
  int p = rt * 16 + r16;             // position (row)
  float v[64];
  #pragma unroll
  for (int i = 0; i < 32; ++i) {
    int c0 = ks * 64 + 2 * i;
    float div = expf((float)c0 * (-9.210340371976184f / (float)DM));
    float ang = (float)p * div;
    v[2*i]   = sinf(ang);
    v[2*i+1] = cosf(ang);
  }
  #pragma unroll
  for (int hf = 0; hf < 2; ++hf) {
    int kt = ks * 2 + hf;
    #pragma unroll
    for (int gg = 0; gg < 4; ++gg) {
      half8 hv, lv;
      #pragma unroll
      for (int j = 0; j < 8; ++j) {
        float x = v[hf * 32 + gg * 8 + j];
        _Float16 h = (_Float16)x;
        hv[j] = h;
        lv[j] = (_Float16)(x - (float)h);
      }
      size_t off = ((size_t)(rt * 32 + kt) * 64 + r16 + gg * 16) * 8;
      *(half8*)(dH + off) = hv;
      *(half8*)(dL + off) = lv;
    }
  }
}

// ---------------- split-fp16 MFMA GEMM (band-aware) ----------------
// Columns >= nsplit get single-pass (hh only): used for the V band whose
// output is consumed as bf16-hi anyway.
#define GBM 128
#define GBN 256

__global__ __launch_bounds__(256, 2) void gemm16(
    const _Float16* __restrict__ AH, const _Float16* __restrict__ AL,
    const _Float16* __restrict__ BH, const _Float16* __restrict__ BL,
    int nsplit,
    u16* __restrict__ o0H, u16* __restrict__ o0L, float s0,
    u16* __restrict__ o1H, u16* __restrict__ o1L, float s1,
    u16* __restrict__ o2H, u16* __restrict__ o2L, float s2) {
  __shared__ _Float16 L[32 * 512];
  int t = threadIdx.x;
  int wv = t >> 6, lane = t & 63;
  int wm = wv >> 1, wn = wv & 1;
  int r16 = lane & 15, g = lane >> 4;
  int m0 = blockIdx.y * GBM;
  int n0 = blockIdx.x * GBN;
  int mt0 = m0 >> 4, nt0 = n0 >> 4;
  bool split = (n0 < nsplit);        // block-uniform

  f32x4 acc[4][8];
  #pragma unroll
  for (int i = 0; i < 4; ++i)
    #pragma unroll
    for (int j = 0; j < 8; ++j) acc[i][j] = (f32x4){0.f, 0.f, 0.f, 0.f};

  for (int kt = 0; kt < 32; ++kt) {
    __syncthreads();
    #pragma unroll
    for (int rd = 0; rd < 8; ++rd) {
      int ci = rd * 4 + wv;
      bool isAlo = (ci < 16) && (ci & 1);
      if (!split && isAlo) continue;         // wave-uniform skip
      const _Float16* src;
      if (ci < 16) {
        int mt = ci >> 1, pl = ci & 1;
        const _Float16* P = pl ? AL : AH;
        src = P + ((size_t)((mt0 + mt) * 32 + kt) * 64 + lane) * 8;
      } else {
        int nt = ci - 16;
        src = BH + ((size_t)((nt0 + nt) * 32 + kt) * 64 + lane) * 8;
      }
      async16(&L[ci * 512], src);
    }
    half8 blo[8];
    if (split) {
      #pragma unroll
      for (int j = 0; j < 8; ++j) {
        int ntg = nt0 + wn * 8 + j;
        blo[j] = *(const half8*)(BL + ((size_t)(ntg * 32 + kt) * 64 + lane) * 8);
      }
    }
    __syncthreads();

    half8 ah[4], al[4];
    #pragma unroll
    for (int i = 0; i < 4; ++i)
      ah[i] = *(const half8*)&L[(((wm * 4 + i) * 2 + 0) * 512) + lane * 8];
    if (split) {
      #pragma unroll
      for (int i = 0; i < 4; ++i)
        al[i] = *(const half8*)&L[(((wm * 4 + i) * 2 + 1) * 512) + lane * 8];
    }
    #pragma unroll
    for (int j = 0; j < 8; ++j) {
      half8 bh = *(const half8*)&L[((16 + wn * 8 + j) * 512) + lane * 8];
      #pragma unroll
      for (int i = 0; i < 4; ++i) {
        acc[i][j] = __builtin_amdgcn_mfma_f32_16x16x32_f16(ah[i], bh, acc[i][j], 0, 0, 0);
        if (split) {
          acc[i][j] = __builtin_amdgcn_mfma_f32_16x16x32_f16(al[i], bh, acc[i][j], 0, 0, 0);
          acc[i][j] = __builtin_amdgcn_mfma_f32_16x16x32_f16(ah[i], blo[j], acc[i][j], 0, 0, 0);
        }
      }
    }
  }

  #pragma unroll
  for (int i = 0; i < 4; ++i)
    #pragma unroll
    for (int j = 0; j < 8; ++j) {
      int col = n0 + wn * 128 + j * 16 + r16;
      int band = col >> 10, lc = col & 1023;
      float sc = band == 0 ? s0 : band == 1 ? s1 : s2;
      u16* oh = band == 0 ? o0H : band == 1 ? o1H : o2H;
      u16* ol = band == 0 ? o0L : band == 1 ? o1L : o2L;
      #pragma unroll
      for (int reg = 0; reg < 4; ++reg) {
        int row = m0 + wm * 64 + i * 16 + g * 4 + reg;
        float c = acc[i][j][reg] * sc;
        u16 hi = f2bf(c);
        oh[(size_t)row * 1024 + lc] = hi;
        if (ol) ol[(size_t)row * 1024 + lc] = f2bf(c - bf2f(hi));
      }
    }
}

// ---------------- pack V (bf16 [B*S][1024] cols h*64+d) -> frag chunks ----------------
__global__ __launch_bounds__(256) void pack_v(const u16* __restrict__ VHg,
    u16* __restrict__ Vf) {
  int sg = blockIdx.x;
  int h = blockIdx.y, b = blockIdx.z;
  int bh = b * NH + h;
  int t = threadIdx.x;
  int r = t >> 2, q = t & 3;
  int s = sg * 64 + r;
  int kc = s >> 5, g = (s >> 3) & 3, j = s & 7;
  const u16* sp = VHg + (size_t)(b * SB + s) * 1024 + h * 64 + q * 16;
  u16 vv[16];
  *(short8*)&vv[0] = *(const short8*)sp;
  *(short8*)&vv[8] = *(const short8*)(sp + 8);
  u16* dp = Vf + ((size_t)(bh * 32 + kc) * 4 + q) * 512 + g * 128 + j;
  #pragma unroll
  for (int e = 0; e < 16; ++e) dp[e * 8] = vv[e];
}

// ---------------- pack K split-bf16 planes -> MFMA B-frag chunks ----------------
__global__ __launch_bounds__(256) void pack_kf(
    const u16* __restrict__ KH, const u16* __restrict__ KL,
    const u16* __restrict__ pKH, const u16* __restrict__ pKL,
    u16* __restrict__ KtfH, u16* __restrict__ KtfL,
    u16* __restrict__ KpfH, u16* __restrict__ KpfL) {
  int sq = blockIdx.x;
  int h = blockIdx.y, z = blockIdx.z;
  int t = threadIdx.x;
  int u = t >> 6, lane = t & 63;
  #pragma unroll
  for (int it = 0; it < 16; ++it) {
    int uu = it * 4 + u;
    int stl = uu >> 2, c = (uu >> 1) & 1, pl = uu & 1;
    int st = sq * 16 + stl;
    size_t roff = (size_t)(st * 16 + (lane & 15)) * 1024 + h * 64 + c * 32 + (lane >> 4) * 8;
    const u16* src;
    u16* dst;
    if (z < BB) {
      src = (pl ? KL : KH) + (size_t)z * SB * 1024 + roff;
      dst = (pl ? KtfL : KtfH) + ((size_t)((z * NH + h) * 64 + st) * 2 + c) * 512 + lane * 8;
    } else {
      src = (pl ? pKL : pKH) + roff;
      dst = (pl ? KpfL : KpfH) + ((size_t)(h * 64 + st) * 2 + c) * 512 + lane * 8;
    }
    *(short8*)dst = *(const short8*)src;
  }
}

// ---------------- bias table transpose: btT[h][rel] ----------------
__global__ __launch_bounds__(256) void btt_kernel(
    const float* __restrict__ bt, float* __restrict__ btT) {
  int h = blockIdx.x;
  for (int r = threadIdx.x; r < 2 * ML; r += 256)
    btT[(size_t)h * (2 * ML) + r] = bt[(size_t)r * NH + h];
}

// ---------------- MFMA flash attention v6 ----------------
// Round-6 structure (barrier-free, direct global B-frags) +
//   XCD swizzle: the 16 q-tiles of one (b,h) share bid%8 -> one XCD's L2
//   holds that (b,h)'s K/V hot set (~3.5MB <= 4MB).
//   Deferred l-reduce (cross-lane sum once at end) + pointer increments.
__global__ __launch_bounds__(256, 4) void attn_mfma6(
    const u16* __restrict__ KtfH, const u16* __restrict__ KtfL,  // [BH][64][2][512]
    const u16* __restrict__ KpfH, const u16* __restrict__ KpfL,  // [H][64][2][512]
    const u16* __restrict__ QHg, const u16* __restrict__ QLg,    // [B*S][1024] (x IS)
    const u16* __restrict__ pQH, const u16* __restrict__ pQL,    // [S][1024] (x IS)
    const u16* __restrict__ Vf,                                   // [BH][32][4][512]
    const float* __restrict__ btT, float* __restrict__ out) {
  __shared__ u16 Pb[4][16 * 72];
  unsigned u = blockIdx.x;
  int xcd = u & 7;
  int rr  = u >> 3;
  int qt  = rr & 15;
  int gsw = rr >> 4;                 // 0..7
  int bh  = gsw * 8 + xcd;           // all qt of (b,h) share u%8
  int b = bh >> 4, h = bh & 15;
  int q0 = qt * 64;
  int t = threadIdx.x;
  int wv = t >> 6, lane = t & 63;
  int g = lane >> 4, r16 = lane & 15;

  // ---- Q fragments (A-layout), hi/lo straight from split planes
  int qrow = q0 + wv * 16 + r16;
  short8 qhi[4], qlo[4];
  #pragma unroll
  for (int c = 0; c < 4; ++c) {
    if (c < 2) {
      size_t off = (size_t)(b * SB + qrow) * 1024 + h * DH + c * 32 + g * 8;
      qhi[c] = *(const short8*)(QHg + off);
      qlo[c] = *(const short8*)(QLg + off);
    } else {
      size_t off = (size_t)qrow * 1024 + h * DH + (c - 2) * 32 + g * 8;
      qhi[c] = *(const short8*)(pQH + off);
      qlo[c] = *(const short8*)(pQL + off);
    }
  }

  f32x4 O[4];
  #pragma unroll
  for (int dt = 0; dt < 4; ++dt) O[dt] = (f32x4){0.f, 0.f, 0.f, 0.f};
  float m_run[4] = {-3e38f, -3e38f, -3e38f, -3e38f};
  float l_run[4] = {0.f, 0.f, 0.f, 0.f};   // lane-local, reduced once at end

  int qbase = q0 + wv * 16 + g * 4;
  const u16* ktH = KtfH + (size_t)(bh * 64) * 1024 + lane * 8;
  const u16* ktL = KtfL + (size_t)(bh * 64) * 1024 + lane * 8;
  const u16* kpH = KpfH + (size_t)(h * 64) * 1024 + lane * 8;
  const u16* kpL = KpfL + (size_t)(h * 64) * 1024 + lane * 8;
  const u16* vp  = Vf + (size_t)(bh * 32) * 2048 + lane * 8;
  const float* bp = btT + (size_t)h * (2 * ML) + ML + r16 - qbase;

  for (int ktr = 0; ktr < 16; ++ktr) {
    // ---- bias gathers first (independent, prefetchable)
    float bias[4][4];
    #pragma unroll
    for (int nt = 0; nt < 4; ++nt)
      #pragma unroll
      for (int reg = 0; reg < 4; ++reg)
        bias[nt][reg] = bp[nt * 16 - reg];

    // ---- QK^T: S = (Qhi+Qlo).(Khi+Klo), 3-term, B-frags direct from global
    f32x4 S[4];
    #pragma unroll
    for (int nt = 0; nt < 4; ++nt) {
      f32x4 acc = (f32x4){0.f, 0.f, 0.f, 0.f};
      #pragma unroll
      for (int c = 0; c < 4; ++c) {
        const u16* ph = (c < 2) ? ktH : kpH;
        const u16* pl = (c < 2) ? ktL : kpL;
        int co = (c < 2) ? c : (c - 2);
        short8 bhi = *(const short8*)(ph + nt * 1024 + co * 512);
        short8 blo = *(const short8*)(pl + nt * 1024 + co * 512);
        acc = __builtin_amdgcn_mfma_f32_16x16x32_bf16(qhi[c], bhi, acc, 0, 0, 0);
        acc = __builtin_amdgcn_mfma_f32_16x16x32_bf16(qlo[c], bhi, acc, 0, 0, 0);
        acc = __builtin_amdgcn_mfma_f32_16x16x32_bf16(qhi[c], blo, acc, 0, 0, 0);
      }
      S[nt] = acc;
    }

    // ---- V prefetch: consumed after softmax
    short8 vfrag[2][4];
    #pragma unroll
    for (int kc = 0; kc < 2; ++kc)
      #pragma unroll
      for (int dt = 0; dt < 4; ++dt)
        vfrag[kc][dt] = *(const short8*)(vp + (kc * 4 + dt) * 512);

    // ---- bias add
    #pragma unroll
    for (int nt = 0; nt < 4; ++nt)
      #pragma unroll
      for (int reg = 0; reg < 4; ++reg)
        S[nt][reg] += bias[nt][reg];

    // ---- online softmax: only the MAX needs a cross-lane reduce per kt
    float tm[4], al[4];
    #pragma unroll
    for (int reg = 0; reg < 4; ++reg)
      tm[reg] = fmaxf(fmaxf(S[0][reg], S[1][reg]), fmaxf(S[2][reg], S[3][reg]));
    #pragma unroll
    for (int off = 1; off < 16; off <<= 1)
      #pragma unroll
      for (int reg = 0; reg < 4; ++reg)
        tm[reg] = fmaxf(tm[reg], __shfl_xor(tm[reg], off, 64));
    #pragma unroll
    for (int reg = 0; reg < 4; ++reg) {
      float mn = fmaxf(m_run[reg], tm[reg]);
      al[reg] = __expf(m_run[reg] - mn);
      m_run[reg] = mn;
    }
    float ts[4] = {0.f, 0.f, 0.f, 0.f};
    #pragma unroll
    for (int nt = 0; nt < 4; ++nt)
      #pragma unroll
      for (int reg = 0; reg < 4; ++reg) {
        float p = __expf(S[nt][reg] - m_run[reg]);
        S[nt][reg] = p;
        ts[reg] += p;
      }
    #pragma unroll
    for (int reg = 0; reg < 4; ++reg)
      l_run[reg] = l_run[reg] * al[reg] + ts[reg];
    #pragma unroll
    for (int dt = 0; dt < 4; ++dt)
      #pragma unroll
      for (int reg = 0; reg < 4; ++reg)
        O[dt][reg] *= al[reg];

    // ---- P (C-layout) -> per-wave LDS -> A-layout frags (wave-local ordering)
    u16* pb = Pb[wv];
    #pragma unroll
    for (int nt = 0; nt < 4; ++nt)
      #pragma unroll
      for (int reg = 0; reg < 4; ++reg)
        pb[(g * 4 + reg) * 72 + nt * 16 + r16] = f2bf(S[nt][reg]);

    // ---- PV with prefetched V frags
    #pragma unroll
    for (int kc = 0; kc < 2; ++kc) {
      short8 pa = *(const short8*)&pb[r16 * 72 + kc * 32 + g * 8];
      #pragma unroll
      for (int dt = 0; dt < 4; ++dt)
        O[dt] = __builtin_amdgcn_mfma_f32_16x16x32_bf16(pa, vfrag[kc][dt], O[dt], 0, 0, 0);
    }

    ktH += 4096; ktL += 4096; kpH += 4096; kpL += 4096;
    vp += 4096; bp += 64;
  }

  // ---- final l reduction across the 16-lane column group, then normalize
  #pragma unroll
  for (int off = 1; off < 16; off <<= 1)
    #pragma unroll
    for (int reg = 0; reg < 4; ++reg)
      l_run[reg] += __shfl_xor(l_run[reg], off, 64);
  #pragma unroll
  for (int reg = 0; reg < 4; ++reg) l_run[reg] = 1.0f / l_run[reg];
  #pragma unroll
  for (int dt = 0; dt < 4; ++dt)
    #pragma unroll
    for (int reg = 0; reg < 4; ++reg)
      out[(size_t)(b * SB + qbase + reg) * DM + h * DH + dt * 16 + r16] =
          O[dt][reg] * l_run[reg];
}

extern "C" void kernel_launch(void* const* d_in, const int* in_sizes, int n_in,
                              void* d_out, int out_size, void* d_ws, size_t ws_size,
                              hipStream_t stream) {
  const float* x     = (const float*)d_in[0];
  const float* gamma = (const float*)d_in[1];
  const float* beta  = (const float*)d_in[2];
  const float* w_pos = (const float*)d_in[3];
  const float* w_tok = (const float*)d_in[4];
  const float* bt    = (const float*)d_in[5];
  float* out = (float*)d_out;
  float* ws  = (float*)d_ws;
  const unsigned M1 = 1u << 20;
  const float IS = 11.313708498984761f;  // sqrt(2*dh)

  // Workspace (f32 units, 19M = 76 MB; overlays only on dead regions):
  _Float16* peH   = (_Float16*)(ws + 1 * M1);         // [1,1.5M)  dead after pos gemm
  _Float16* peL   = (_Float16*)(ws + 1 * M1 + M1/2);  // [1.5,2M)
  _Float16* wpH   = (_Float16*)(ws + 2 * M1);         // [2,3M)    dead after pos gemm
  _Float16* wpL   = (_Float16*)(ws + 3 * M1);         // [3,4M)
  u16*      posKH = (u16*)(ws + 4 * M1);              // [4,4.5M)  dead after pack_kf
  u16*      posKL = (u16*)(ws + 4 * M1 + M1/2);       // [4.5,5M)
  u16*      posQH = (u16*)(ws + 5 * M1);              // [5,5.5M)  live -> attn
  u16*      posQL = (u16*)(ws + 5 * M1 + M1/2);       // [5.5,6M)
  float*    XN    = ws + 6 * M1;                      // [6,10M)   dead after pack16
  _Float16* xnH   = (_Float16*)(ws + 10 * M1);        // [10,12M)  dead after tok gemm
  _Float16* xnL   = (_Float16*)(ws + 12 * M1);        // [12,14M)  dead after tok gemm
  _Float16* wtH   = (_Float16*)(ws + 14 * M1);        // [14,15.5M) dead after tok gemm
  _Float16* wtL   = (_Float16*)(ws + 15 * M1 + M1/2); // [15.5,17M)
  u16*      KH    = (u16*)(ws);                       // [0,2M)    dead after pack_kf
  u16*      KL    = (u16*)(ws + 2 * M1);              // [2,4M)    over wpHL; dead after pack_kf
  u16*      QH    = (u16*)(ws + 6 * M1);              // [6,8M)    over XN; live -> attn
  u16*      QL    = (u16*)(ws + 8 * M1);              // [8,10M)
  u16*      VH    = (u16*)(ws + 17 * M1);             // [17,19M)  dead after pack_v
  u16*      Vf    = (u16*)(ws + 10 * M1);             // [10,12M)  over xnH; live -> attn
  float*    btT   = ws + 12 * M1;                     // [12,12.25M) over xnL
  u16*      KpfH  = (u16*)(ws + 12 * M1 + M1/4);      // [12.25,12.75M) 2 MB
  u16*      KpfL  = (u16*)(ws + 12 * M1 + 3*M1/4);    // [12.75,13.25M)
  u16*      KtfH  = (u16*)(ws + 13 * M1 + M1/4);      // [13.25,15.25M) 8 MB
  u16*      KtfL  = (u16*)(ws + 15 * M1 + M1/4);      // [15.25,17.25M)

  pe_pack16<<<SB / 16, 256, 0, stream>>>(peH, peL);
  pack16<<<(2 * DM) / 16, 256, 0, stream>>>(w_pos, wpH, wpL, 32.0f);
  gemm16<<<dim3((2 * DM) / GBN, SB / GBM), 256, 0, stream>>>(
      peH, peL, wpH, wpL, 2 * DM,
      posKH, posKL, 1.0f / 32.0f,
      posQH, posQL, IS / 32.0f,
      posKH, posKL, 1.0f / 32.0f);
  ln_kernel<<<BB * SB, 256, 0, stream>>>(x, gamma, beta, XN);
  pack16<<<(BB * SB) / 16, 256, 0, stream>>>(XN, xnH, xnL, 1.0f);
  pack16<<<(3 * DM) / 16, 256, 0, stream>>>(w_tok, wtH, wtL, 32.0f);
  gemm16<<<dim3((3 * DM) / GBN, (BB * SB) / GBM), 256, 0, stream>>>(
      xnH, xnL, wtH, wtL, 2 * DM,          // V band (cols >= 2048): hh-only
      KH, KL, 1.0f / 32.0f,
      QH, QL, IS / 32.0f,
      VH, (u16*)nullptr, 1.0f / 32.0f);
  pack_v<<<dim3(SB / 64, NH, BB), 256, 0, stream>>>(VH, Vf);   // must precede pack_kf (KtfL overlays VH head)
  pack_kf<<<dim3(4, NH, BB + 1), 256, 0, stream>>>(KH, KL, posKH, posKL,
                                                   KtfH, KtfL, KpfH, KpfL);
  btt_kernel<<<NH, 256, 0, stream>>>(bt, btT);
  attn_mfma6<<<BB * NH * (SB / 64), 256, 0, stream>>>(
      KtfH, KtfL, KpfH, KpfL, QH, QL, posQH, posQL, Vf, btT, out);
}

// Round 9
// 367.264 us; speedup vs baseline: 1.5401x; 1.2641x over previous
//
#include <hip/hip_runtime.h>
#include <math.h>

#define SB 1024   // seq len
#define DM 1024   // d_model
#define BB 4      // batch
#define NH 16     // heads
#define DH 64     // head dim
#define ML 1024   // MAX_LEN

typedef __attribute__((ext_vector_type(8))) short short8;
typedef __attribute__((ext_vector_type(8))) _Float16 half8;
typedef __attribute__((ext_vector_type(4))) float f32x4;
typedef unsigned short u16;

__device__ __forceinline__ u16 f2bf(float x) {
  unsigned u = __float_as_uint(x);
  u += 0x7fffu + ((u >> 16) & 1u);
  return (u16)(u >> 16);
}
__device__ __forceinline__ float bf2f(u16 h) { return __uint_as_float((unsigned)h << 16); }

// async global->LDS, 16B per lane; lds base must be wave-uniform (HW adds lane*16)
__device__ __forceinline__ void async16(void* lds, const void* g) {
  __builtin_amdgcn_global_load_lds(
      (const __attribute__((address_space(1))) unsigned*)g,
      (__attribute__((address_space(3))) unsigned*)lds, 16, 0, 0);
}

// ---------------- layernorm (fp32 out) ----------------
__device__ __forceinline__ float block_sum256(float s, float* red) {
  #pragma unroll
  for (int o = 32; o > 0; o >>= 1) s += __shfl_down(s, o, 64);
  int t = threadIdx.x;
  if ((t & 63) == 0) red[t >> 6] = s;
  __syncthreads();
  float tot = red[0] + red[1] + red[2] + red[3];
  __syncthreads();
  return tot;
}

__global__ __launch_bounds__(256) void ln_kernel(const float* __restrict__ x,
    const float* __restrict__ gamma, const float* __restrict__ beta,
    float* __restrict__ xn) {
  __shared__ float red[4];
  int row = blockIdx.x;
  const float4* xr = (const float4*)(x + (size_t)row * DM);
  int t = threadIdx.x;
  float4 v = xr[t];
  float mu = block_sum256(v.x + v.y + v.z + v.w, red) * (1.0f / DM);
  float4 d = {v.x - mu, v.y - mu, v.z - mu, v.w - mu};
  float var = block_sum256(d.x*d.x + d.y*d.y + d.z*d.z + d.w*d.w, red) * (1.0f / DM);
  float rstd = rsqrtf(var + 1e-5f);
  float4 g  = ((const float4*)gamma)[t];
  float4 bb = ((const float4*)beta)[t];
  float4 o = {d.x * rstd * g.x + bb.x, d.y * rstd * g.y + bb.y,
              d.z * rstd * g.z + bb.z, d.w * rstd * g.w + bb.w};
  ((float4*)(xn + (size_t)row * DM))[t] = o;
}

// ---------------- pack fp32 [R][1024] -> split-fp16 frag-chunk planes ----------------
__global__ __launch_bounds__(256) void pack16(const float* __restrict__ src,
    _Float16* __restrict__ dH, _Float16* __restrict__ dL, float scale) {
  int rt = blockIdx.x;
  int t = threadIdx.x;
  int r16 = t >> 4, ks = t & 15;
  const float* sp = src + (size_t)(rt * 16 + r16) * 1024 + ks * 64;
  float v[64];
  #pragma unroll
  for (int i = 0; i < 16; ++i) {
    float4 f = *(const float4*)(sp + i * 4);
    v[i*4+0] = f.x; v[i*4+1] = f.y; v[i*4+2] = f.z; v[i*4+3] = f.w;
  }
  #pragma unroll
  for (int hf = 0; hf < 2; ++hf) {
    int kt = ks * 2 + hf;
    #pragma unroll
    for (int gg = 0; gg < 4; ++gg) {
      half8 hv, lv;
      #pragma unroll
      for (int j = 0; j < 8; ++j) {
        float x = v[hf * 32 + gg * 8 + j] * scale;
        _Float16 h = (_Float16)x;
        hv[j] = h;
        lv[j] = (_Float16)(x - (float)h);
      }
      size_t off = ((size_t)(rt * 32 + kt) * 64 + r16 + gg * 16) * 8;
      *(half8*)(dH + off) = hv;
      *(half8*)(dL + off) = lv;
    }
  }
}

// ---------------- fused: sinusoidal PE -> split-fp16 frag planes ----------------
__global__ __launch_bounds__(256) void pe_pack16(_Float16* __restrict__ dH,
    _Float16* __restrict__ dL) {
  int rt = blockIdx.x;
  int t = threadIdx.x;
  int r16 = t >> 4, ks = t & 15;
  int p = rt * 16 + r16;             // position (row)
  float v[64];
  #pragma unroll
  for (int i = 0; i < 32; ++i) {
    int c0 = ks * 64 + 2 * i;
    float div = expf((float)c0 * (-9.210340371976184f / (float)DM));
    float ang = (float)p * div;
    v[2*i]   = sinf(ang);
    v[2*i+1] = cosf(ang);
  }
  #pragma unroll
  for (int hf = 0; hf < 2; ++hf) {
    int kt = ks * 2 + hf;
    #pragma unroll
    for (int gg = 0; gg < 4; ++gg) {
      half8 hv, lv;
      #pragma unroll
      for (int j = 0; j < 8; ++j) {
        float x = v[hf * 32 + gg * 8 + j];
        _Float16 h = (_Float16)x;
        hv[j] = h;
        lv[j] = (_Float16)(x - (float)h);
      }
      size_t off = ((size_t)(rt * 32 + kt) * 64 + r16 + gg * 16) * 8;
      *(half8*)(dH + off) = hv;
      *(half8*)(dL + off) = lv;
    }
  }
}

// ---------------- split-fp16 MFMA GEMM (band-aware) ----------------
// Columns >= nsplit get single-pass (hh only): used for the V band whose
// output is consumed as bf16-hi anyway.
#define GBM 128
#define GBN 256

__global__ __launch_bounds__(256, 2) void gemm16(
    const _Float16* __restrict__ AH, const _Float16* __restrict__ AL,
    const _Float16* __restrict__ BH, const _Float16* __restrict__ BL,
    int nsplit,
    u16* __restrict__ o0H, u16* __restrict__ o0L, float s0,
    u16* __restrict__ o1H, u16* __restrict__ o1L, float s1,
    u16* __restrict__ o2H, u16* __restrict__ o2L, float s2) {
  __shared__ _Float16 L[32 * 512];
  int t = threadIdx.x;
  int wv = t >> 6, lane = t & 63;
  int wm = wv >> 1, wn = wv & 1;
  int r16 = lane & 15, g = lane >> 4;
  int m0 = blockIdx.y * GBM;
  int n0 = blockIdx.x * GBN;
  int mt0 = m0 >> 4, nt0 = n0 >> 4;
  bool split = (n0 < nsplit);        // block-uniform

  f32x4 acc[4][8];
  #pragma unroll
  for (int i = 0; i < 4; ++i)
    #pragma unroll
    for (int j = 0; j < 8; ++j) acc[i][j] = (f32x4){0.f, 0.f, 0.f, 0.f};

  for (int kt = 0; kt < 32; ++kt) {
    __syncthreads();
    #pragma unroll
    for (int rd = 0; rd < 8; ++rd) {
      int ci = rd * 4 + wv;
      bool isAlo = (ci < 16) && (ci & 1);
      if (!split && isAlo) continue;         // wave-uniform skip
      const _Float16* src;
      if (ci < 16) {
        int mt = ci >> 1, pl = ci & 1;
        const _Float16* P = pl ? AL : AH;
        src = P + ((size_t)((mt0 + mt) * 32 + kt) * 64 + lane) * 8;
      } else {
        int nt = ci - 16;
        src = BH + ((size_t)((nt0 + nt) * 32 + kt) * 64 + lane) * 8;
      }
      async16(&L[ci * 512], src);
    }
    half8 blo[8];
    if (split) {
      #pragma unroll
      for (int j = 0; j < 8; ++j) {
        int ntg = nt0 + wn * 8 + j;
        blo[j] = *(const half8*)(BL + ((size_t)(ntg * 32 + kt) * 64 + lane) * 8);
      }
    }
    __syncthreads();

    half8 ah[4], al[4];
    #pragma unroll
    for (int i = 0; i < 4; ++i)
      ah[i] = *(const half8*)&L[(((wm * 4 + i) * 2 + 0) * 512) + lane * 8];
    if (split) {
      #pragma unroll
      for (int i = 0; i < 4; ++i)
        al[i] = *(const half8*)&L[(((wm * 4 + i) * 2 + 1) * 512) + lane * 8];
    }
    #pragma unroll
    for (int j = 0; j < 8; ++j) {
      half8 bh = *(const half8*)&L[((16 + wn * 8 + j) * 512) + lane * 8];
      #pragma unroll
      for (int i = 0; i < 4; ++i) {
        acc[i][j] = __builtin_amdgcn_mfma_f32_16x16x32_f16(ah[i], bh, acc[i][j], 0, 0, 0);
        if (split) {
          acc[i][j] = __builtin_amdgcn_mfma_f32_16x16x32_f16(al[i], bh, acc[i][j], 0, 0, 0);
          acc[i][j] = __builtin_amdgcn_mfma_f32_16x16x32_f16(ah[i], blo[j], acc[i][j], 0, 0, 0);
        }
      }
    }
  }

  #pragma unroll
  for (int i = 0; i < 4; ++i)
    #pragma unroll
    for (int j = 0; j < 8; ++j) {
      int col = n0 + wn * 128 + j * 16 + r16;
      int band = col >> 10, lc = col & 1023;
      float sc = band == 0 ? s0 : band == 1 ? s1 : s2;
      u16* oh = band == 0 ? o0H : band == 1 ? o1H : o2H;
      u16* ol = band == 0 ? o0L : band == 1 ? o1L : o2L;
      #pragma unroll
      for (int reg = 0; reg < 4; ++reg) {
        int row = m0 + wm * 64 + i * 16 + g * 4 + reg;
        float c = acc[i][j][reg] * sc;
        u16 hi = f2bf(c);
        oh[(size_t)row * 1024 + lc] = hi;
        if (ol) ol[(size_t)row * 1024 + lc] = f2bf(c - bf2f(hi));
      }
    }
}

// ---------------- pack V (bf16 [B*S][1024] cols h*64+d) -> frag chunks ----------------
__global__ __launch_bounds__(256) void pack_v(const u16* __restrict__ VHg,
    u16* __restrict__ Vf) {
  int sg = blockIdx.x;
  int h = blockIdx.y, b = blockIdx.z;
  int bh = b * NH + h;
  int t = threadIdx.x;
  int r = t >> 2, q = t & 3;
  int s = sg * 64 + r;
  int kc = s >> 5, g = (s >> 3) & 3, j = s & 7;
  const u16* sp = VHg + (size_t)(b * SB + s) * 1024 + h * 64 + q * 16;
  u16 vv[16];
  *(short8*)&vv[0] = *(const short8*)sp;
  *(short8*)&vv[8] = *(const short8*)(sp + 8);
  u16* dp = Vf + ((size_t)(bh * 32 + kc) * 4 + q) * 512 + g * 128 + j;
  #pragma unroll
  for (int e = 0; e < 16; ++e) dp[e * 8] = vv[e];
}

// ---------------- pack K split-bf16 planes -> MFMA B-frag chunks ----------------
__global__ __launch_bounds__(256) void pack_kf(
    const u16* __restrict__ KH, const u16* __restrict__ KL,
    const u16* __restrict__ pKH, const u16* __restrict__ pKL,
    u16* __restrict__ KtfH, u16* __restrict__ KtfL,
    u16* __restrict__ KpfH, u16* __restrict__ KpfL) {
  int sq = blockIdx.x;
  int h = blockIdx.y, z = blockIdx.z;
  int t = threadIdx.x;
  int u = t >> 6, lane = t & 63;
  #pragma unroll
  for (int it = 0; it < 16; ++it) {
    int uu = it * 4 + u;
    int stl = uu >> 2, c = (uu >> 1) & 1, pl = uu & 1;
    int st = sq * 16 + stl;
    size_t roff = (size_t)(st * 16 + (lane & 15)) * 1024 + h * 64 + c * 32 + (lane >> 4) * 8;
    const u16* src;
    u16* dst;
    if (z < BB) {
      src = (pl ? KL : KH) + (size_t)z * SB * 1024 + roff;
      dst = (pl ? KtfL : KtfH) + ((size_t)((z * NH + h) * 64 + st) * 2 + c) * 512 + lane * 8;
    } else {
      src = (pl ? pKL : pKH) + roff;
      dst = (pl ? KpfL : KpfH) + ((size_t)(h * 64 + st) * 2 + c) * 512 + lane * 8;
    }
    *(short8*)dst = *(const short8*)src;
  }
}

// ---------------- bias table transpose: btT[h][rel] ----------------
__global__ __launch_bounds__(256) void btt_kernel(
    const float* __restrict__ bt, float* __restrict__ btT) {
  int h = blockIdx.x;
  for (int r = threadIdx.x; r < 2 * ML; r += 256)
    btT[(size_t)h * (2 * ML) + r] = bt[(size_t)r * NH + h];
}

// ---------------- MFMA flash attention v7: 32 q-rows/wave, 2 chains ----------------
// Each wave carries TWO Q A-fragment sets (rows +0 and +16): every K/V B-frag
// load now feeds 2x the MFMA work (halves L2 traffic), and the two independent
// S-chains interleave through MFMA + shfl trees (doubles per-wave ILP).
// Block = 128 q-rows, grid 512 (2 blocks/CU). No XCD swizzle (r8: regression).
// __launch_bounds__(256,2): 256-VGPR budget, no spill (r7 spilled at 64-budget).
__global__ __launch_bounds__(256, 2) void attn_mfma7(
    const u16* __restrict__ KtfH, const u16* __restrict__ KtfL,  // [BH][64][2][512]
    const u16* __restrict__ KpfH, const u16* __restrict__ KpfL,  // [H][64][2][512]
    const u16* __restrict__ QHg, const u16* __restrict__ QLg,    // [B*S][1024] (x IS)
    const u16* __restrict__ pQH, const u16* __restrict__ pQL,    // [S][1024] (x IS)
    const u16* __restrict__ Vf,                                   // [BH][32][4][512]
    const float* __restrict__ btT, float* __restrict__ out) {
  __shared__ u16 Pb[4][2][16 * 72];
  int bid = blockIdx.x;
  int qt = bid & 7;                  // 8 q-tiles of 128 rows
  int bh = bid >> 3;
  int b = bh >> 4, h = bh & 15;
  int q0 = qt * 128;
  int t = threadIdx.x;
  int wv = t >> 6, lane = t & 63;
  int g = lane >> 4, r16 = lane & 15;

  // ---- Q fragments (A-layout) for both chains
  short8 qhi[2][4], qlo[2][4];
  #pragma unroll
  for (int cc = 0; cc < 2; ++cc) {
    int qrow = q0 + wv * 32 + cc * 16 + r16;
    #pragma unroll
    for (int c = 0; c < 4; ++c) {
      if (c < 2) {
        size_t off = (size_t)(b * SB + qrow) * 1024 + h * DH + c * 32 + g * 8;
        qhi[cc][c] = *(const short8*)(QHg + off);
        qlo[cc][c] = *(const short8*)(QLg + off);
      } else {
        size_t off = (size_t)qrow * 1024 + h * DH + (c - 2) * 32 + g * 8;
        qhi[cc][c] = *(const short8*)(pQH + off);
        qlo[cc][c] = *(const short8*)(pQL + off);
      }
    }
  }

  f32x4 O[2][4];
  #pragma unroll
  for (int cc = 0; cc < 2; ++cc)
    #pragma unroll
    for (int dt = 0; dt < 4; ++dt) O[cc][dt] = (f32x4){0.f, 0.f, 0.f, 0.f};
  float m_run[2][4], l_run[2][4];
  #pragma unroll
  for (int cc = 0; cc < 2; ++cc)
    #pragma unroll
    for (int reg = 0; reg < 4; ++reg) { m_run[cc][reg] = -3e38f; l_run[cc][reg] = 0.f; }

  int qb0 = q0 + wv * 32 + g * 4;    // chain-0 C-layout row base; chain 1: +16
  const u16* ktH = KtfH + (size_t)(bh * 64) * 1024 + lane * 8;
  const u16* ktL = KtfL + (size_t)(bh * 64) * 1024 + lane * 8;
  const u16* kpH = KpfH + (size_t)(h * 64) * 1024 + lane * 8;
  const u16* kpL = KpfL + (size_t)(h * 64) * 1024 + lane * 8;
  const u16* vp  = Vf + (size_t)(bh * 32) * 2048 + lane * 8;
  const float* bp0 = btT + (size_t)h * (2 * ML) + ML + r16 - qb0;
  const float* bp1 = bp0 - 16;

  for (int ktr = 0; ktr < 16; ++ktr) {
    // ---- bias gathers first (independent, prefetchable)
    float bias[2][4][4];
    #pragma unroll
    for (int nt = 0; nt < 4; ++nt)
      #pragma unroll
      for (int reg = 0; reg < 4; ++reg) {
        bias[0][nt][reg] = bp0[nt * 16 - reg];
        bias[1][nt][reg] = bp1[nt * 16 - reg];
      }

    // ---- QK^T: both chains share each K B-frag (3-term split each)
    f32x4 S[2][4];
    #pragma unroll
    for (int nt = 0; nt < 4; ++nt) {
      f32x4 a0 = (f32x4){0.f, 0.f, 0.f, 0.f};
      f32x4 a1 = (f32x4){0.f, 0.f, 0.f, 0.f};
      #pragma unroll
      for (int c = 0; c < 4; ++c) {
        const u16* ph = (c < 2) ? ktH : kpH;
        const u16* pl = (c < 2) ? ktL : kpL;
        int co = (c < 2) ? c : (c - 2);
        short8 bhi = *(const short8*)(ph + nt * 1024 + co * 512);
        short8 blo = *(const short8*)(pl + nt * 1024 + co * 512);
        a0 = __builtin_amdgcn_mfma_f32_16x16x32_bf16(qhi[0][c], bhi, a0, 0, 0, 0);
        a1 = __builtin_amdgcn_mfma_f32_16x16x32_bf16(qhi[1][c], bhi, a1, 0, 0, 0);
        a0 = __builtin_amdgcn_mfma_f32_16x16x32_bf16(qlo[0][c], bhi, a0, 0, 0, 0);
        a1 = __builtin_amdgcn_mfma_f32_16x16x32_bf16(qlo[1][c], bhi, a1, 0, 0, 0);
        a0 = __builtin_amdgcn_mfma_f32_16x16x32_bf16(qhi[0][c], blo, a0, 0, 0, 0);
        a1 = __builtin_amdgcn_mfma_f32_16x16x32_bf16(qhi[1][c], blo, a1, 0, 0, 0);
      }
      S[0][nt] = a0; S[1][nt] = a1;
    }

    // ---- V prefetch: shared by both chains, consumed after softmax
    short8 vfrag[2][4];
    #pragma unroll
    for (int kc = 0; kc < 2; ++kc)
      #pragma unroll
      for (int dt = 0; dt < 4; ++dt)
        vfrag[kc][dt] = *(const short8*)(vp + (kc * 4 + dt) * 512);

    // ---- bias add + online softmax (two chains interleave through the trees)
    #pragma unroll
    for (int cc = 0; cc < 2; ++cc)
      #pragma unroll
      for (int nt = 0; nt < 4; ++nt)
        #pragma unroll
        for (int reg = 0; reg < 4; ++reg)
          S[cc][nt][reg] += bias[cc][nt][reg];

    float tm[2][4], al[2][4];
    #pragma unroll
    for (int cc = 0; cc < 2; ++cc)
      #pragma unroll
      for (int reg = 0; reg < 4; ++reg)
        tm[cc][reg] = fmaxf(fmaxf(S[cc][0][reg], S[cc][1][reg]),
                            fmaxf(S[cc][2][reg], S[cc][3][reg]));
    #pragma unroll
    for (int off = 1; off < 16; off <<= 1)
      #pragma unroll
      for (int cc = 0; cc < 2; ++cc)
        #pragma unroll
        for (int reg = 0; reg < 4; ++reg)
          tm[cc][reg] = fmaxf(tm[cc][reg], __shfl_xor(tm[cc][reg], off, 64));
    #pragma unroll
    for (int cc = 0; cc < 2; ++cc)
      #pragma unroll
      for (int reg = 0; reg < 4; ++reg) {
        float mn = fmaxf(m_run[cc][reg], tm[cc][reg]);
        al[cc][reg] = __expf(m_run[cc][reg] - mn);
        m_run[cc][reg] = mn;
      }
    float ts[2][4] = {{0.f, 0.f, 0.f, 0.f}, {0.f, 0.f, 0.f, 0.f}};
    #pragma unroll
    for (int cc = 0; cc < 2; ++cc)
      #pragma unroll
      for (int nt = 0; nt < 4; ++nt)
        #pragma unroll
        for (int reg = 0; reg < 4; ++reg) {
          float p = __expf(S[cc][nt][reg] - m_run[cc][reg]);
          S[cc][nt][reg] = p;
          ts[cc][reg] += p;
        }
    #pragma unroll
    for (int cc = 0; cc < 2; ++cc)
      #pragma unroll
      for (int reg = 0; reg < 4; ++reg)
        l_run[cc][reg] = l_run[cc][reg] * al[cc][reg] + ts[cc][reg];
    #pragma unroll
    for (int cc = 0; cc < 2; ++cc)
      #pragma unroll
      for (int dt = 0; dt < 4; ++dt)
        #pragma unroll
        for (int reg = 0; reg < 4; ++reg)
          O[cc][dt][reg] *= al[cc][reg];

    // ---- P (C-layout) -> per-wave LDS -> A-layout frags (wave-local ordering)
    #pragma unroll
    for (int cc = 0; cc < 2; ++cc) {
      u16* pb = Pb[wv][cc];
      #pragma unroll
      for (int nt = 0; nt < 4; ++nt)
        #pragma unroll
        for (int reg = 0; reg < 4; ++reg)
          pb[(g * 4 + reg) * 72 + nt * 16 + r16] = f2bf(S[cc][nt][reg]);
    }

    // ---- PV: V frags shared across chains
    #pragma unroll
    for (int kc = 0; kc < 2; ++kc) {
      #pragma unroll
      for (int cc = 0; cc < 2; ++cc) {
        short8 pa = *(const short8*)&Pb[wv][cc][r16 * 72 + kc * 32 + g * 8];
        #pragma unroll
        for (int dt = 0; dt < 4; ++dt)
          O[cc][dt] = __builtin_amdgcn_mfma_f32_16x16x32_bf16(pa, vfrag[kc][dt], O[cc][dt], 0, 0, 0);
      }
    }

    ktH += 4096; ktL += 4096; kpH += 4096; kpL += 4096;
    vp += 4096; bp0 += 64; bp1 += 64;
  }

  // ---- final l reduction across the 16-lane column group, then normalize
  #pragma unroll
  for (int off = 1; off < 16; off <<= 1)
    #pragma unroll
    for (int cc = 0; cc < 2; ++cc)
      #pragma unroll
      for (int reg = 0; reg < 4; ++reg)
        l_run[cc][reg] += __shfl_xor(l_run[cc][reg], off, 64);
  #pragma unroll
  for (int cc = 0; cc < 2; ++cc)
    #pragma unroll
    for (int reg = 0; reg < 4; ++reg) l_run[cc][reg] = 1.0f / l_run[cc][reg];
  #pragma unroll
  for (int cc = 0; cc < 2; ++cc)
    #pragma unroll
    for (int dt = 0; dt < 4; ++dt)
      #pragma unroll
      for (int reg = 0; reg < 4; ++reg)
        out[(size_t)(b * SB + qb0 + cc * 16 + reg) * DM + h * DH + dt * 16 + r16] =
            O[cc][dt][reg] * l_run[cc][reg];
}

extern "C" void kernel_launch(void* const* d_in, const int* in_sizes, int n_in,
                              void* d_out, int out_size, void* d_ws, size_t ws_size,
                              hipStream_t stream) {
  const float* x     = (const float*)d_in[0];
  const float* gamma = (const float*)d_in[1];
  const float* beta  = (const float*)d_in[2];
  const float* w_pos = (const float*)d_in[3];
  const float* w_tok = (const float*)d_in[4];
  const float* bt    = (const float*)d_in[5];
  float* out = (float*)d_out;
  float* ws  = (float*)d_ws;
  const unsigned M1 = 1u << 20;
  const float IS = 11.313708498984761f;  // sqrt(2*dh)

  // Workspace (f32 units, 19M = 76 MB; overlays only on dead regions):
  _Float16* peH   = (_Float16*)(ws + 1 * M1);         // [1,1.5M)  dead after pos gemm
  _Float16* peL   = (_Float16*)(ws + 1 * M1 + M1/2);  // [1.5,2M)
  _Float16* wpH   = (_Float16*)(ws + 2 * M1);         // [2,3M)    dead after pos gemm
  _Float16* wpL   = (_Float16*)(ws + 3 * M1);         // [3,4M)
  u16*      posKH = (u16*)(ws + 4 * M1);              // [4,4.5M)  dead after pack_kf
  u16*      posKL = (u16*)(ws + 4 * M1 + M1/2);       // [4.5,5M)
  u16*      posQH = (u16*)(ws + 5 * M1);              // [5,5.5M)  live -> attn
  u16*      posQL = (u16*)(ws + 5 * M1 + M1/2);       // [5.5,6M)
  float*    XN    = ws + 6 * M1;                      // [6,10M)   dead after pack16
  _Float16* xnH   = (_Float16*)(ws + 10 * M1);        // [10,12M)  dead after tok gemm
  _Float16* xnL   = (_Float16*)(ws + 12 * M1);        // [12,14M)  dead after tok gemm
  _Float16* wtH   = (_Float16*)(ws + 14 * M1);        // [14,15.5M) dead after tok gemm
  _Float16* wtL   = (_Float16*)(ws + 15 * M1 + M1/2); // [15.5,17M)
  u16*      KH    = (u16*)(ws);                       // [0,2M)    dead after pack_kf
  u16*      KL    = (u16*)(ws + 2 * M1);              // [2,4M)    over wpHL; dead after pack_kf
  u16*      QH    = (u16*)(ws + 6 * M1);              // [6,8M)    over XN; live -> attn
  u16*      QL    = (u16*)(ws + 8 * M1);              // [8,10M)
  u16*      VH    = (u16*)(ws + 17 * M1);             // [17,19M)  dead after pack_v
  u16*      Vf    = (u16*)(ws + 10 * M1);             // [10,12M)  over xnH; live -> attn
  float*    btT   = ws + 12 * M1;                     // [12,12.25M) over xnL
  u16*      KpfH  = (u16*)(ws + 12 * M1 + M1/4);      // [12.25,12.75M) 2 MB
  u16*      KpfL  = (u16*)(ws + 12 * M1 + 3*M1/4);    // [12.75,13.25M)
  u16*      KtfH  = (u16*)(ws + 13 * M1 + M1/4);      // [13.25,15.25M) 8 MB
  u16*      KtfL  = (u16*)(ws + 15 * M1 + M1/4);      // [15.25,17.25M)

  pe_pack16<<<SB / 16, 256, 0, stream>>>(peH, peL);
  pack16<<<(2 * DM) / 16, 256, 0, stream>>>(w_pos, wpH, wpL, 32.0f);
  gemm16<<<dim3((2 * DM) / GBN, SB / GBM), 256, 0, stream>>>(
      peH, peL, wpH, wpL, 2 * DM,
      posKH, posKL, 1.0f / 32.0f,
      posQH, posQL, IS / 32.0f,
      posKH, posKL, 1.0f / 32.0f);
  ln_kernel<<<BB * SB, 256, 0, stream>>>(x, gamma, beta, XN);
  pack16<<<(BB * SB) / 16, 256, 0, stream>>>(XN, xnH, xnL, 1.0f);
  pack16<<<(3 * DM) / 16, 256, 0, stream>>>(w_tok, wtH, wtL, 32.0f);
  gemm16<<<dim3((3 * DM) / GBN, (BB * SB) / GBM), 256, 0, stream>>>(
      xnH, xnL, wtH, wtL, 2 * DM,          // V band (cols >= 2048): hh-only
      KH, KL, 1.0f / 32.0f,
      QH, QL, IS / 32.0f,
      VH, (u16*)nullptr, 1.0f / 32.0f);
  pack_v<<<dim3(SB / 64, NH, BB), 256, 0, stream>>>(VH, Vf);   // must precede pack_kf (KtfL overlays VH head)
  pack_kf<<<dim3(4, NH, BB + 1), 256, 0, stream>>>(KH, KL, posKH, posKL,
                                                   KtfH, KtfL, KpfH, KpfL);
  btt_kernel<<<NH, 256, 0, stream>>>(bt, btT);
  attn_mfma7<<<BB * NH * (SB / 128), 256, 0, stream>>>(
      KtfH, KtfL, KpfH, KpfL, QH, QL, posQH, posQL, Vf, btT, out);
}